// Round 7
// baseline (132.746 us; speedup 1.0000x reference)
//
#include <hip/hip_runtime.h>

// Dense image warp (bilinear, tfa interpolate_bilinear semantics)
// x:    [B, H, W, C] fp32   (B=4, H=512, W=512, C=64)
// flow: [B, H, W, 2] fp32
// out:  [B, H, W, C] fp32
//
// R7: A/B experiment — exactly R4 (97.0 us) but with NORMAL stores instead of
// non-temporal. Isolates the store path: nt stores bypass L2 (128B
// write-through over the fabric, poor DRAM efficiency) while normal stores
// accumulate in L2 and write back full lines (the 7 TB/s fill kernel uses
// normal stores). Counter-risk: out now allocates in L2/L3 and may evict x.
// Everything else identical: 8 lanes/px x 2 float4 chunks, XCD slab swizzle,
// nt flow load.

typedef float f32x4 __attribute__((ext_vector_type(4)));
typedef float f32x2 __attribute__((ext_vector_type(2)));

constexpr int BD = 4;
constexpr int HD = 512;
constexpr int WD = 512;
constexpr int CD = 64;
constexpr int NBLOCKS = BD * HD * WD * 8 / 256;   // 32768
constexpr int NXCD = 8;
constexpr int CHUNK = NBLOCKS / NXCD;             // 4096 (exact)

__global__ __launch_bounds__(256) void warp_bilinear_kernel(
    const float* __restrict__ x,
    const float* __restrict__ flow,
    float* __restrict__ out)
{
    // XCD swizzle: each XCD gets a contiguous slab of the image.
    const int bid = (blockIdx.x & (NXCD - 1)) * CHUNK + (blockIdx.x >> 3);

    const int gtid = bid * 256 + threadIdx.x;
    const int p    = gtid >> 3;          // pixel index in [0, B*H*W)
    const int sub  = gtid & 7;           // lane within pixel
    const int c0   = sub << 2;           // channels c0..c0+3 and c0+32..c0+35

    // p = ((b*H + h)*W + w)
    const int w  = p & (WD - 1);
    const int hb = p >> 9;               // p / W
    const int h  = hb & (HD - 1);
    const int b  = hb >> 9;              // hb / H

    const f32x2 fl =
        __builtin_nontemporal_load(reinterpret_cast<const f32x2*>(flow) + p);
    const float qx = (float)w + fl.x;
    const float qy = (float)h + fl.y;

    // tfa: floor clamped to [0, size-2], alpha clamped to [0, 1]
    float fxf = fminf(fmaxf(floorf(qx), 0.0f), (float)(WD - 2));
    float fyf = fminf(fmaxf(floorf(qy), 0.0f), (float)(HD - 2));
    const float ax = fminf(fmaxf(qx - fxf, 0.0f), 1.0f);
    const float ay = fminf(fmaxf(qy - fyf, 0.0f), 1.0f);
    const int fx = (int)fxf;
    const int fy = (int)fyf;

    const size_t base_idx = ((((size_t)b * HD + fy) * WD + fx) * CD) + c0;
    const float* base = x + base_idx;
    const float* baseb = base + (size_t)WD * CD;   // row fy+1

    // 8 independent gather loads (max MLP), then compute.
    const f32x4 tl0 = *reinterpret_cast<const f32x4*>(base);
    const f32x4 tl1 = *reinterpret_cast<const f32x4*>(base + 32);
    const f32x4 tr0 = *reinterpret_cast<const f32x4*>(base + CD);
    const f32x4 tr1 = *reinterpret_cast<const f32x4*>(base + CD + 32);
    const f32x4 bl0 = *reinterpret_cast<const f32x4*>(baseb);
    const f32x4 bl1 = *reinterpret_cast<const f32x4*>(baseb + 32);
    const f32x4 br0 = *reinterpret_cast<const f32x4*>(baseb + CD);
    const f32x4 br1 = *reinterpret_cast<const f32x4*>(baseb + CD + 32);

    f32x4 it0 = (tr0 - tl0) * ax + tl0;
    f32x4 ib0 = (br0 - bl0) * ax + bl0;
    f32x4 o0  = (ib0 - it0) * ay + it0;

    f32x4 it1 = (tr1 - tl1) * ax + tl1;
    f32x4 ib1 = (br1 - bl1) * ax + bl1;
    f32x4 o1  = (ib1 - it1) * ay + it1;

    // NORMAL stores (the A/B variable vs R4)
    f32x4* op = reinterpret_cast<f32x4*>(out + (size_t)p * CD + c0);
    op[0] = o0;
    op[8] = o1;   // +32 floats
}

extern "C" void kernel_launch(void* const* d_in, const int* in_sizes, int n_in,
                              void* d_out, int out_size, void* d_ws, size_t ws_size,
                              hipStream_t stream) {
    const float* x    = (const float*)d_in[0];
    const float* flow = (const float*)d_in[1];
    float* out        = (float*)d_out;

    warp_bilinear_kernel<<<NBLOCKS, 256, 0, stream>>>(x, flow, out);
}

// Round 8
// 124.746 us; speedup vs baseline: 1.0641x; 1.0641x over previous
//
#include <hip/hip_runtime.h>

// Dense image warp (bilinear, tfa interpolate_bilinear semantics)
// x:    [B, H, W, C] fp32   (B=4, H=512, W=512, C=64)
// flow: [B, H, W, 2] fp32
// out:  [B, H, W, C] fp32
//
// R8: cache-asymmetry flip (A/B vs R4=97.0us and R7=132.7us).
//  - R4: normal x loads + nt out stores  -> L3 holds ~half of x, out streams.
//  - R7: normal x loads + normal stores  -> x and out thrash L3 -> 132us.
//  - R8: NT x loads + NORMAL out stores  -> out (268MB ~ L3 256MB) owns L3,
//    writes mostly die in L3 / write back full lines via L2; x streams from
//    HBM (268MB, the same bytes L3 was only half-saving anyway).
//  Everything else identical to R4: 8 lanes/px x 2 float4 chunks, XCD slab
//  swizzle, nt flow load, 32768 one-shot blocks x 256 threads.

typedef float f32x4 __attribute__((ext_vector_type(4)));
typedef float f32x2 __attribute__((ext_vector_type(2)));

constexpr int BD = 4;
constexpr int HD = 512;
constexpr int WD = 512;
constexpr int CD = 64;
constexpr int NBLOCKS = BD * HD * WD * 8 / 256;   // 32768
constexpr int NXCD = 8;
constexpr int CHUNK = NBLOCKS / NXCD;             // 4096 (exact)

__global__ __launch_bounds__(256) void warp_bilinear_kernel(
    const float* __restrict__ x,
    const float* __restrict__ flow,
    float* __restrict__ out)
{
    // XCD swizzle: each XCD gets a contiguous slab of the image.
    const int bid = (blockIdx.x & (NXCD - 1)) * CHUNK + (blockIdx.x >> 3);

    const int gtid = bid * 256 + threadIdx.x;
    const int p    = gtid >> 3;          // pixel index in [0, B*H*W)
    const int sub  = gtid & 7;           // lane within pixel
    const int c0   = sub << 2;           // channels c0..c0+3 and c0+32..c0+35

    // p = ((b*H + h)*W + w)
    const int w  = p & (WD - 1);
    const int hb = p >> 9;               // p / W
    const int h  = hb & (HD - 1);
    const int b  = hb >> 9;              // hb / H

    const f32x2 fl =
        __builtin_nontemporal_load(reinterpret_cast<const f32x2*>(flow) + p);
    const float qx = (float)w + fl.x;
    const float qy = (float)h + fl.y;

    // tfa: floor clamped to [0, size-2], alpha clamped to [0, 1]
    float fxf = fminf(fmaxf(floorf(qx), 0.0f), (float)(WD - 2));
    float fyf = fminf(fmaxf(floorf(qy), 0.0f), (float)(HD - 2));
    const float ax = fminf(fmaxf(qx - fxf, 0.0f), 1.0f);
    const float ay = fminf(fmaxf(qy - fyf, 0.0f), 1.0f);
    const int fx = (int)fxf;
    const int fy = (int)fyf;

    const size_t base_idx = ((((size_t)b * HD + fy) * WD + fx) * CD) + c0;
    const float* base = x + base_idx;
    const float* baseb = base + (size_t)WD * CD;   // row fy+1

    // 8 independent gather loads — NON-TEMPORAL (stream x, don't hold L3)
    const f32x4 tl0 = __builtin_nontemporal_load(reinterpret_cast<const f32x4*>(base));
    const f32x4 tl1 = __builtin_nontemporal_load(reinterpret_cast<const f32x4*>(base + 32));
    const f32x4 tr0 = __builtin_nontemporal_load(reinterpret_cast<const f32x4*>(base + CD));
    const f32x4 tr1 = __builtin_nontemporal_load(reinterpret_cast<const f32x4*>(base + CD + 32));
    const f32x4 bl0 = __builtin_nontemporal_load(reinterpret_cast<const f32x4*>(baseb));
    const f32x4 bl1 = __builtin_nontemporal_load(reinterpret_cast<const f32x4*>(baseb + 32));
    const f32x4 br0 = __builtin_nontemporal_load(reinterpret_cast<const f32x4*>(baseb + CD));
    const f32x4 br1 = __builtin_nontemporal_load(reinterpret_cast<const f32x4*>(baseb + CD + 32));

    f32x4 it0 = (tr0 - tl0) * ax + tl0;
    f32x4 ib0 = (br0 - bl0) * ax + bl0;
    f32x4 o0  = (ib0 - it0) * ay + it0;

    f32x4 it1 = (tr1 - tl1) * ax + tl1;
    f32x4 ib1 = (br1 - bl1) * ax + bl1;
    f32x4 o1  = (ib1 - it1) * ay + it1;

    // NORMAL stores: out (~268MB ~ L3 size) owns L2/L3 retention.
    f32x4* op = reinterpret_cast<f32x4*>(out + (size_t)p * CD + c0);
    op[0] = o0;
    op[8] = o1;   // +32 floats
}

extern "C" void kernel_launch(void* const* d_in, const int* in_sizes, int n_in,
                              void* d_out, int out_size, void* d_ws, size_t ws_size,
                              hipStream_t stream) {
    const float* x    = (const float*)d_in[0];
    const float* flow = (const float*)d_in[1];
    float* out        = (float*)d_out;

    warp_bilinear_kernel<<<NBLOCKS, 256, 0, stream>>>(x, flow, out);
}

// Round 9
// 97.019 us; speedup vs baseline: 1.3682x; 1.2858x over previous
//
#include <hip/hip_runtime.h>

// Dense image warp (bilinear, tfa interpolate_bilinear semantics)
// x:    [B, H, W, C] fp32   (B=4, H=512, W=512, C=64)
// flow: [B, H, W, 2] fp32
// out:  [B, H, W, C] fp32
//
// R9 = R4 restored (best config, 97.0 us). Completed 2x2 cache-hint A/B:
//   normal loads + nt stores   = 97.0   <- this kernel
//   normal loads + normal st.  = 132.7  (out thrashes x in L2/L3)
//   nt loads + normal stores   = 124.7
// Binding resource: cross-fabric mixed-traffic path (~536 MB irreducible:
// 268 MB gathered x reads + 268 MB out writes) at ~5.5 TB/s effective vs
// 6.3 TB/s streaming-copy ceiling; residual is DRAM row-buffer inefficiency
// on randomly-gathered x misses. VALU (9%), occupancy (58-70%), MLP, and
// block persistence all tested and non-binding.
//
// Structure: 8 lanes/px, 2 float4 channel chunks/thread, XCD slab swizzle,
// nt flow load, nt out stores, 32768 one-shot blocks x 256 threads.

typedef float f32x4 __attribute__((ext_vector_type(4)));
typedef float f32x2 __attribute__((ext_vector_type(2)));

constexpr int BD = 4;
constexpr int HD = 512;
constexpr int WD = 512;
constexpr int CD = 64;
constexpr int NBLOCKS = BD * HD * WD * 8 / 256;   // 32768
constexpr int NXCD = 8;
constexpr int CHUNK = NBLOCKS / NXCD;             // 4096 (exact)

__global__ __launch_bounds__(256) void warp_bilinear_kernel(
    const float* __restrict__ x,
    const float* __restrict__ flow,
    float* __restrict__ out)
{
    // XCD swizzle: each XCD gets a contiguous slab of the image.
    const int bid = (blockIdx.x & (NXCD - 1)) * CHUNK + (blockIdx.x >> 3);

    const int gtid = bid * 256 + threadIdx.x;
    const int p    = gtid >> 3;          // pixel index in [0, B*H*W)
    const int sub  = gtid & 7;           // lane within pixel
    const int c0   = sub << 2;           // channels c0..c0+3 and c0+32..c0+35

    // p = ((b*H + h)*W + w)
    const int w  = p & (WD - 1);
    const int hb = p >> 9;               // p / W
    const int h  = hb & (HD - 1);
    const int b  = hb >> 9;              // hb / H

    const f32x2 fl =
        __builtin_nontemporal_load(reinterpret_cast<const f32x2*>(flow) + p);
    const float qx = (float)w + fl.x;
    const float qy = (float)h + fl.y;

    // tfa: floor clamped to [0, size-2], alpha clamped to [0, 1]
    float fxf = fminf(fmaxf(floorf(qx), 0.0f), (float)(WD - 2));
    float fyf = fminf(fmaxf(floorf(qy), 0.0f), (float)(HD - 2));
    const float ax = fminf(fmaxf(qx - fxf, 0.0f), 1.0f);
    const float ay = fminf(fmaxf(qy - fyf, 0.0f), 1.0f);
    const int fx = (int)fxf;
    const int fy = (int)fyf;

    const size_t base_idx = ((((size_t)b * HD + fy) * WD + fx) * CD) + c0;
    const float* base = x + base_idx;
    const float* baseb = base + (size_t)WD * CD;   // row fy+1

    // 8 independent gather loads (max MLP), then compute.
    const f32x4 tl0 = *reinterpret_cast<const f32x4*>(base);
    const f32x4 tl1 = *reinterpret_cast<const f32x4*>(base + 32);
    const f32x4 tr0 = *reinterpret_cast<const f32x4*>(base + CD);
    const f32x4 tr1 = *reinterpret_cast<const f32x4*>(base + CD + 32);
    const f32x4 bl0 = *reinterpret_cast<const f32x4*>(baseb);
    const f32x4 bl1 = *reinterpret_cast<const f32x4*>(baseb + 32);
    const f32x4 br0 = *reinterpret_cast<const f32x4*>(baseb + CD);
    const f32x4 br1 = *reinterpret_cast<const f32x4*>(baseb + CD + 32);

    f32x4 it0 = (tr0 - tl0) * ax + tl0;
    f32x4 ib0 = (br0 - bl0) * ax + bl0;
    f32x4 o0  = (ib0 - it0) * ay + it0;

    f32x4 it1 = (tr1 - tl1) * ax + tl1;
    f32x4 ib1 = (br1 - bl1) * ax + bl1;
    f32x4 o1  = (ib1 - it1) * ay + it1;

    f32x4* op = reinterpret_cast<f32x4*>(out + (size_t)p * CD + c0);
    __builtin_nontemporal_store(o0, op);
    __builtin_nontemporal_store(o1, op + 8);   // +32 floats
}

extern "C" void kernel_launch(void* const* d_in, const int* in_sizes, int n_in,
                              void* d_out, int out_size, void* d_ws, size_t ws_size,
                              hipStream_t stream) {
    const float* x    = (const float*)d_in[0];
    const float* flow = (const float*)d_in[1];
    float* out        = (float*)d_out;

    warp_bilinear_kernel<<<NBLOCKS, 256, 0, stream>>>(x, flow, out);
}